// Round 7
// baseline (129.122 us; speedup 1.0000x reference)
//
#include <hip/hip_runtime.h>
#include <math.h>

// DecomposedFrequencyLearning: NaN-fill -> rfft(4096) -> 4x freq mask -> irfft
// x[32,4096,64] f32  ->  out[4,32,4096,64] f32
//
// R7: R6 structure (one WG per (batch,pair), single fwd FFT, bf16 spectrum
// park, 4x mask+inverse) + explicit occupancy target:
//   __attribute__((amdgpu_waves_per_eu(4)))  -> VGPR cap 512/4 = 128
//   -> 4 WG/CU -> grid 1024 = exactly one dispatch round, no 256-WG tail.
// (R3/R6 unclamped: 140 VGPR -> 3 WG/CU + two rounds, dur 117us, all pipes
// idle. __launch_bounds__(256,4) is NOT equivalent: this toolchain turns it
// into a 64-VGPR target and spills massively — R2/R4.)
// Register diet to fit 128: w4m/w64r rematerialized at use sites; wm/w16r
// re-read from wtab inside the filter loop (shorter live ranges).
// pad(v)=v+(v>>4) keeps all LDS exchange patterns bank-uniform.

namespace {

constexpr int NFFT = 4096;
constexpr int NT   = 256;
constexpr int NB   = 32;
constexpr int NC   = 64;
constexpr int KF   = 4;

__device__ __forceinline__ int pad(int i) { return i + (i >> 4); }

__device__ __forceinline__ float2 cadd(float2 a, float2 b){ return make_float2(a.x+b.x, a.y+b.y); }
__device__ __forceinline__ float2 csub(float2 a, float2 b){ return make_float2(a.x-b.x, a.y-b.y); }
__device__ __forceinline__ float2 cmul(float2 a, float2 b){
    return make_float2(fmaf(a.x,b.x,-(a.y*b.y)), fmaf(a.x,b.y, a.y*b.x));
}
// a * conj(b)
__device__ __forceinline__ float2 cmulc(float2 a, float2 b){
    return make_float2(fmaf(a.x,b.x, a.y*b.y), fmaf(a.y,b.x,-(a.x*b.y)));
}

// f32 -> bf16 (round-nearest-even), returned in low 16 bits
__device__ __forceinline__ unsigned bfrne(float f){
    unsigned u = __float_as_uint(f);
    return (u + 0x7FFFu + ((u >> 16) & 1u)) >> 16;
}

__device__ __forceinline__ void bf4_fwd(float2&a,float2&b,float2&c,float2&d){
    float2 t0=cadd(a,c), t1=csub(a,c), t2=cadd(b,d), t3=csub(b,d);
    float2 mi3=make_float2(t3.y,-t3.x);          // -i*t3
    a=cadd(t0,t2); b=cadd(t1,mi3); c=csub(t0,t2); d=csub(t1,mi3);
}
__device__ __forceinline__ void bf4_inv(float2&a,float2&b,float2&c,float2&d){
    float2 t0=cadd(a,c), t1=csub(a,c), t2=cadd(b,d), t3=csub(b,d);
    float2 pi3=make_float2(-t3.y,t3.x);          // +i*t3
    a=cadd(t0,t2); b=cadd(t1,pi3); c=csub(t0,t2); d=csub(t1,pi3);
}
// DIF: butterfly then twiddle outputs 1..3
__device__ __forceinline__ void grp_fwd(float2&a,float2&b,float2&c,float2&d,
                                        float2 w1, float2 w2, float2 w3){
    bf4_fwd(a,b,c,d);
    b=cmul(b,w1); c=cmul(c,w2); d=cmul(d,w3);
}
__device__ __forceinline__ void xgrp_fwd(float2&a,float2&b,float2&c,float2&d, float2 w1){
    float2 w2=cmul(w1,w1), w3=cmul(w2,w1);
    grp_fwd(a,b,c,d,w1,w2,w3);
}
// DIT: conj-twiddle inputs 1..3 then butterfly
__device__ __forceinline__ void grp_inv(float2&a,float2&b,float2&c,float2&d,
                                        float2 w1, float2 w2, float2 w3){
    b=cmulc(b,w1); c=cmulc(c,w2); d=cmulc(d,w3);
    bf4_inv(a,b,c,d);
}
__device__ __forceinline__ void xgrp_inv(float2&a,float2&b,float2&c,float2&d, float2 w1){
    float2 w2=cmul(w1,w1), w3=cmul(w2,w1);
    grp_inv(a,b,c,d,w1,w2,w3);
}

__global__ __launch_bounds__(NT)
__attribute__((amdgpu_waves_per_eu(4)))
void dfl_kernel(const float* __restrict__ x,
                const int* __restrict__ taus,
                const int* __restrict__ mus,
                float* __restrict__ out)
{
    __shared__ float2 buf[NFFT + NFFT/16];   // 4352*8 = 34816 B
    __shared__ float2 wtab[512];             // 4096 B ; total 38912 -> 4 WG/CU

    const int tid = threadIdx.x;
    // XCD-chunked swizzle: the 32 WGs sharing a batch land on one XCD so L2
    // merges their 8B-per-lane partial-line loads/stores.
    const int l  = ((blockIdx.x & 7) << 7) | (blockIdx.x >> 3);
    const int b  = l >> 5;
    const int c0 = (l & 31) << 1;
    const float QNAN = __uint_as_float(0x7fc00000u);

    // w(j) = exp(-2*pi*i*j/4096), j<512
    for (int j = tid; j < 512; j += NT) {
        float s, c; sincosf(-3.14159265358979f * (float)j / 2048.0f, &s, &c);
        wtab[j] = make_float2(c, s);
    }

    float2* chLast  = buf;        // [256] scratch, overwritten later
    float2* chFirst = buf + 256;  // [256]

    // ---- load + in-chunk forward fill (thread t owns times [16t,16t+16)) ----
    const float* xb = x + ((size_t)b * NFFT) * NC + c0;
    float2 z[16];
    float2 last = make_float2(QNAN, QNAN), first = make_float2(QNAN, QNAN);
    #pragma unroll
    for (int j = 0; j < 16; ++j) {
        float2 v = *reinterpret_cast<const float2*>(xb + (size_t)(16*tid + j) * NC);
        if (first.x != first.x && v.x == v.x) first.x = v.x;
        if (first.y != first.y && v.y == v.y) first.y = v.y;
        if (v.x == v.x) last.x = v.x; else v.x = last.x;
        if (v.y == v.y) last.y = v.y; else v.y = last.y;
        z[j] = v;                               // NaN only in leading run
    }
    chLast[tid] = last;
    chFirst[tid] = first;
    __syncthreads();                            // S1: wtab + scans visible

    // last observed before this chunk
    float2 pre = make_float2(QNAN, QNAN);
    for (int kk = tid - 1; kk >= 0; --kk) {
        float2 s2 = chLast[kk];
        if (pre.x != pre.x) pre.x = s2.x;
        if (pre.y != pre.y) pre.y = s2.y;
        if (pre.x == pre.x && pre.y == pre.y) break;
    }
    // globally first observed (backward-fill value for the leading prefix)
    float2 gfirst = make_float2(QNAN, QNAN);
    for (int kk = 0; kk < NT; ++kk) {
        float2 s2 = chFirst[kk];
        if (gfirst.x != gfirst.x) gfirst.x = s2.x;
        if (gfirst.y != gfirst.y) gfirst.y = s2.y;
        if (gfirst.x == gfirst.x && gfirst.y == gfirst.y) break;
    }
    if (gfirst.x != gfirst.x) gfirst.x = 0.f;   // all-NaN -> 0
    if (gfirst.y != gfirst.y) gfirst.y = 0.f;
    const float fx = (pre.x == pre.x) ? pre.x : gfirst.x;
    const float fy = (pre.y == pre.y) ? pre.y : gfirst.y;
    #pragma unroll
    for (int j = 0; j < 16; ++j) {
        if (z[j].x != z[j].x) z[j].x = fx;
        if (z[j].y != z[j].y) z[j].y = fy;
    }

    const float2 W1 = make_float2( 0.92387953251f,-0.38268343236f); // w(256)
    const float2 W2 = make_float2( 0.70710678119f,-0.70710678119f); // w(512)
    const float2 W3 = make_float2( 0.38268343236f,-0.92387953251f); // w(768)
    const float2 W4 = make_float2( 0.f,-1.f);                       // w(1024)
    const float2 W6 = make_float2(-0.70710678119f,-0.70710678119f); // w(1536)
    const float2 W9 = make_float2(-0.92387953251f, 0.38268343236f); // w(2304)

    __syncthreads();                            // S2: scans done, buf reusable

    // ---- write x_clean at P3 (natural time) ----
    #pragma unroll
    for (int j = 0; j < 16; ++j) buf[pad(16*tid + j)] = z[j];
    __syncthreads();                            // S3

    // ================= forward DIF =================
    // phase A on P1 (n = m + 256j)
    #pragma unroll
    for (int j = 0; j < 16; ++j) z[j] = buf[pad(tid + 256*j)];
    {   const float2 wm = wtab[tid];
        xgrp_fwd(z[0],z[4],z[8],z[12], wm);
        xgrp_fwd(z[1],z[5],z[9],z[13], cmul(wm,W1));
        xgrp_fwd(z[2],z[6],z[10],z[14], cmul(wm,W2));
        xgrp_fwd(z[3],z[7],z[11],z[15], cmul(wm,W3));
        float2 q2 = cmul(wm, wm);
        float2 w1 = cmul(q2, q2);                 // w(4m) rematerialized
        float2 w2 = cmul(w1,w1), w3 = cmul(w2,w1);
        grp_fwd(z[0],z[1],z[2],z[3],  w1,w2,w3);
        grp_fwd(z[4],z[5],z[6],z[7],  w1,w2,w3);
        grp_fwd(z[8],z[9],z[10],z[11],w1,w2,w3);
        grp_fwd(z[12],z[13],z[14],z[15],w1,w2,w3);
    }
    #pragma unroll
    for (int j = 0; j < 16; ++j) buf[pad(tid + 256*j)] = z[j];
    __syncthreads();                            // S4

    // phase B on P2 (n = (m>>4)*256 + (m&15) + 16j)
    const int p2b = ((tid >> 4) << 8) + (tid & 15);
    #pragma unroll
    for (int j = 0; j < 16; ++j) z[j] = buf[pad(p2b + 16*j)];
    {   const float2 w16r = wtab[16 * (tid & 15)];
        xgrp_fwd(z[0],z[4],z[8],z[12], w16r);
        xgrp_fwd(z[1],z[5],z[9],z[13], cmul(w16r,W1));
        xgrp_fwd(z[2],z[6],z[10],z[14], cmul(w16r,W2));
        xgrp_fwd(z[3],z[7],z[11],z[15], cmul(w16r,W3));
        float2 q3 = cmul(w16r, w16r);
        float2 w1 = cmul(q3, q3);                 // w(64r) rematerialized
        float2 w2 = cmul(w1,w1), w3 = cmul(w2,w1);
        grp_fwd(z[0],z[1],z[2],z[3],  w1,w2,w3);
        grp_fwd(z[4],z[5],z[6],z[7],  w1,w2,w3);
        grp_fwd(z[8],z[9],z[10],z[11],w1,w2,w3);
        grp_fwd(z[12],z[13],z[14],z[15],w1,w2,w3);
    }
    #pragma unroll
    for (int j = 0; j < 16; ++j) buf[pad(p2b + 16*j)] = z[j];
    __syncthreads();                            // S5

    // phase C on P3 (n = 16m + j)
    #pragma unroll
    for (int j = 0; j < 16; ++j) z[j] = buf[pad(16*tid + j)];
    bf4_fwd(z[0],z[4],z[8],z[12]);
    grp_fwd(z[1],z[5],z[9],z[13], W1,W2,W3);
    grp_fwd(z[2],z[6],z[10],z[14], W2,W4,W6);
    grp_fwd(z[3],z[7],z[11],z[15], W3,W6,W9);
    bf4_fwd(z[0],z[1],z[2],z[3]);
    bf4_fwd(z[4],z[5],z[6],z[7]);
    bf4_fwd(z[8],z[9],z[10],z[11]);
    bf4_fwd(z[12],z[13],z[14],z[15]);

    // ---- park spectrum scaled by 1/N, packed bf16 (re lo | im hi) ----
    const float scale = 1.0f / (float)NFFT;
    unsigned spec_bf[16];
    #pragma unroll
    for (int j = 0; j < 16; ++j)
        spec_bf[j] = bfrne(z[j].x * scale) | (bfrne(z[j].y * scale) << 16);

    // digit-reverse of tid (4 base-4 digits)
    const int revtid = ((tid & 3) << 6) | (((tid >> 2) & 3) << 4)
                     | (((tid >> 4) & 3) << 2) | (tid >> 6);

    // ================= per-filter inverse DIT =================
    #pragma unroll 1
    for (int k = 0; k < KF; ++k) {
        const int tau = taus[k];
        const int mu  = mus[k];
        __syncthreads();                        // prior reads of buf complete

        // mask + unpack in regs (P3 position n = 16m+j, freq = rev4(n))
        #pragma unroll
        for (int j = 0; j < 16; ++j) {
            const int r = revtid + ((j & 3) << 10) + ((j >> 2) << 8);
            const int f = (r <= 2048) ? r : (NFFT - r);
            const bool keep = (mu == 1) ? (f < tau) : (f >= tau);
            const unsigned p = spec_bf[j];
            z[j] = keep ? make_float2(__uint_as_float(p << 16),
                                      __uint_as_float(p & 0xFFFF0000u))
                        : make_float2(0.f, 0.f);
        }
        // stage0: Y-groups, no twiddle
        bf4_inv(z[0],z[1],z[2],z[3]);
        bf4_inv(z[4],z[5],z[6],z[7]);
        bf4_inv(z[8],z[9],z[10],z[11]);
        bf4_inv(z[12],z[13],z[14],z[15]);
        // stage1: X-groups, k1 = 256*jp (constants)
        bf4_inv(z[0],z[4],z[8],z[12]);
        grp_inv(z[1],z[5],z[9],z[13], W1,W2,W3);
        grp_inv(z[2],z[6],z[10],z[14], W2,W4,W6);
        grp_inv(z[3],z[7],z[11],z[15], W3,W6,W9);
        #pragma unroll
        for (int j = 0; j < 16; ++j) buf[pad(16*tid + j)] = z[j];
        __syncthreads();

        #pragma unroll
        for (int j = 0; j < 16; ++j) z[j] = buf[pad(p2b + 16*j)];
        // stage2: Y-groups, k1 = 64r (rematerialized from wtab)
        {   const float2 w16r = wtab[16 * (tid & 15)];
            float2 q3 = cmul(w16r, w16r);
            float2 w1 = cmul(q3, q3);
            float2 w2 = cmul(w1,w1), w3 = cmul(w2,w1);
            grp_inv(z[0],z[1],z[2],z[3],  w1,w2,w3);
            grp_inv(z[4],z[5],z[6],z[7],  w1,w2,w3);
            grp_inv(z[8],z[9],z[10],z[11],w1,w2,w3);
            grp_inv(z[12],z[13],z[14],z[15],w1,w2,w3);
            // stage3: X-groups, k1 = 16r + 256*jp
            xgrp_inv(z[0],z[4],z[8],z[12], w16r);
            xgrp_inv(z[1],z[5],z[9],z[13], cmul(w16r,W1));
            xgrp_inv(z[2],z[6],z[10],z[14], cmul(w16r,W2));
            xgrp_inv(z[3],z[7],z[11],z[15], cmul(w16r,W3));
        }
        #pragma unroll
        for (int j = 0; j < 16; ++j) buf[pad(p2b + 16*j)] = z[j];
        __syncthreads();

        #pragma unroll
        for (int j = 0; j < 16; ++j) z[j] = buf[pad(tid + 256*j)];
        // stage4: Y-groups, k1 = 4m (rematerialized from wtab)
        {   const float2 wm = wtab[tid];
            float2 q2 = cmul(wm, wm);
            float2 w1 = cmul(q2, q2);
            float2 w2 = cmul(w1,w1), w3 = cmul(w2,w1);
            grp_inv(z[0],z[1],z[2],z[3],  w1,w2,w3);
            grp_inv(z[4],z[5],z[6],z[7],  w1,w2,w3);
            grp_inv(z[8],z[9],z[10],z[11],w1,w2,w3);
            grp_inv(z[12],z[13],z[14],z[15],w1,w2,w3);
            // stage5: X-groups, k1 = m + 256*jp
            xgrp_inv(z[0],z[4],z[8],z[12], wm);
            xgrp_inv(z[1],z[5],z[9],z[13], cmul(wm,W1));
            xgrp_inv(z[2],z[6],z[10],z[14], cmul(wm,W2));
            xgrp_inv(z[3],z[7],z[11],z[15], cmul(wm,W3));
        }

        // store natural order: thread m owns t = m + 256j
        float* ob = out + ((size_t)(k*NB + b) * NFFT) * NC + c0;
        #pragma unroll
        for (int j = 0; j < 16; ++j) {
            const int t = tid + 256*j;
            *reinterpret_cast<float2*>(ob + (size_t)t * NC) = z[j];
        }
    }
}

} // namespace

extern "C" void kernel_launch(void* const* d_in, const int* in_sizes, int n_in,
                              void* d_out, int out_size, void* d_ws, size_t ws_size,
                              hipStream_t stream) {
    (void)in_sizes; (void)n_in; (void)out_size; (void)d_ws; (void)ws_size;
    const float* x  = (const float*)d_in[0];
    const int* taus = (const int*)d_in[1];
    const int* mus  = (const int*)d_in[2];
    float* out      = (float*)d_out;
    dfl_kernel<<<dim3(NB * NC / 2), dim3(NT), 0, stream>>>(x, taus, mus, out);
}

// Round 9
// 102.019 us; speedup vs baseline: 1.2657x; 1.2657x over previous
//
#include <hip/hip_runtime.h>
#include <math.h>

// DecomposedFrequencyLearning: NaN-fill -> rfft(4096) -> 4x freq mask -> irfft
// x[32,4096,64] f32  ->  out[4,32,4096,64] f32
//
// R9 = R8 with the cvt_pkrtz typedef fixed (__fp16 ext vector, not _Float16).
// Structure: one WG per (batch,pair), single fwd FFT, spectrum parked in LDS
// (fp16-packed), 4x mask+inverse.
//  - exchange buffer bufh: half2-packed u32[4352] (17408 B)
//  - spectrum spech:       half2-packed u32[4352] (17408 B)
//  - wtab float2[512]      (4096 B)           total 38912 B -> 4 WG/CU
// Removing spec[16] from registers (R5 measured 104 VGPR for the no-park
// body) should land <=128 unclamped -> 4 waves/SIMD -> grid 1024 = one
// dispatch round, no 256-WG tail (R3/R6: 140 VGPR, 3 WG/CU, two rounds).
// NO occupancy attribute: __launch_bounds__(256,4) AND amdgpu_waves_per_eu(4)
// both make hipcc target 64 VGPR and spill to scratch (R2/R4/R7).
// 1/N prescale before the forward keeps all fp16 intermediates in range.
// pad(v)=v+(v>>4) keeps exchange patterns ~conflict-free for u32 banks.

namespace {

constexpr int NFFT = 4096;
constexpr int NT   = 256;
constexpr int NB   = 32;
constexpr int NC   = 64;
constexpr int KF   = 4;

typedef __fp16 h2 __attribute__((ext_vector_type(2)));

__device__ __forceinline__ int pad(int i) { return i + (i >> 4); }

__device__ __forceinline__ unsigned packh(float x, float y){
    h2 h = __builtin_amdgcn_cvt_pkrtz(x, y);   // v_cvt_pkrtz_f16_f32
    return __builtin_bit_cast(unsigned, h);
}
__device__ __forceinline__ float2 unpackh(unsigned u){
    h2 h = __builtin_bit_cast(h2, u);
    return make_float2((float)h.x, (float)h.y);
}

__device__ __forceinline__ float2 cadd(float2 a, float2 b){ return make_float2(a.x+b.x, a.y+b.y); }
__device__ __forceinline__ float2 csub(float2 a, float2 b){ return make_float2(a.x-b.x, a.y-b.y); }
__device__ __forceinline__ float2 cmul(float2 a, float2 b){
    return make_float2(fmaf(a.x,b.x,-(a.y*b.y)), fmaf(a.x,b.y, a.y*b.x));
}
// a * conj(b)
__device__ __forceinline__ float2 cmulc(float2 a, float2 b){
    return make_float2(fmaf(a.x,b.x, a.y*b.y), fmaf(a.y,b.x,-(a.x*b.y)));
}

__device__ __forceinline__ void bf4_fwd(float2&a,float2&b,float2&c,float2&d){
    float2 t0=cadd(a,c), t1=csub(a,c), t2=cadd(b,d), t3=csub(b,d);
    float2 mi3=make_float2(t3.y,-t3.x);          // -i*t3
    a=cadd(t0,t2); b=cadd(t1,mi3); c=csub(t0,t2); d=csub(t1,mi3);
}
__device__ __forceinline__ void bf4_inv(float2&a,float2&b,float2&c,float2&d){
    float2 t0=cadd(a,c), t1=csub(a,c), t2=cadd(b,d), t3=csub(b,d);
    float2 pi3=make_float2(-t3.y,t3.x);          // +i*t3
    a=cadd(t0,t2); b=cadd(t1,pi3); c=csub(t0,t2); d=csub(t1,pi3);
}
// DIF: butterfly then twiddle outputs 1..3
__device__ __forceinline__ void grp_fwd(float2&a,float2&b,float2&c,float2&d,
                                        float2 w1, float2 w2, float2 w3){
    bf4_fwd(a,b,c,d);
    b=cmul(b,w1); c=cmul(c,w2); d=cmul(d,w3);
}
__device__ __forceinline__ void xgrp_fwd(float2&a,float2&b,float2&c,float2&d, float2 w1){
    float2 w2=cmul(w1,w1), w3=cmul(w2,w1);
    grp_fwd(a,b,c,d,w1,w2,w3);
}
// DIT: conj-twiddle inputs 1..3 then butterfly
__device__ __forceinline__ void grp_inv(float2&a,float2&b,float2&c,float2&d,
                                        float2 w1, float2 w2, float2 w3){
    b=cmulc(b,w1); c=cmulc(c,w2); d=cmulc(d,w3);
    bf4_inv(a,b,c,d);
}
__device__ __forceinline__ void xgrp_inv(float2&a,float2&b,float2&c,float2&d, float2 w1){
    float2 w2=cmul(w1,w1), w3=cmul(w2,w1);
    grp_inv(a,b,c,d,w1,w2,w3);
}

__global__ __launch_bounds__(NT)
void dfl_kernel(const float* __restrict__ x,
                const int* __restrict__ taus,
                const int* __restrict__ mus,
                float* __restrict__ out)
{
    __shared__ unsigned bufh[NFFT + NFFT/16];   // 17408 B, half2-packed
    __shared__ unsigned spech[NFFT + NFFT/16];  // 17408 B, half2-packed park
    __shared__ float2 wtab[512];                // 4096 B  (total 38912)

    const int tid = threadIdx.x;
    // XCD-chunked swizzle: the 32 WGs sharing a batch land on one XCD so L2
    // merges their 8B-per-lane partial-line loads/stores.
    const int l  = ((blockIdx.x & 7) << 7) | (blockIdx.x >> 3);
    const int b  = l >> 5;
    const int c0 = (l & 31) << 1;
    const float QNAN = __uint_as_float(0x7fc00000u);

    // w(j) = exp(-2*pi*i*j/4096), j<512
    for (int j = tid; j < 512; j += NT) {
        float s, c; sincosf(-3.14159265358979f * (float)j / 2048.0f, &s, &c);
        wtab[j] = make_float2(c, s);
    }

    // scan scratch aliases the (not-yet-used) spectrum region
    float2* chLast  = reinterpret_cast<float2*>(spech);        // [256]
    float2* chFirst = reinterpret_cast<float2*>(spech) + 256;  // [256]

    // ---- load + in-chunk forward fill (thread t owns times [16t,16t+16)) ----
    const float* xb = x + ((size_t)b * NFFT) * NC + c0;
    float2 z[16];
    float2 last = make_float2(QNAN, QNAN), first = make_float2(QNAN, QNAN);
    #pragma unroll
    for (int j = 0; j < 16; ++j) {
        float2 v = *reinterpret_cast<const float2*>(xb + (size_t)(16*tid + j) * NC);
        if (first.x != first.x && v.x == v.x) first.x = v.x;
        if (first.y != first.y && v.y == v.y) first.y = v.y;
        if (v.x == v.x) last.x = v.x; else v.x = last.x;
        if (v.y == v.y) last.y = v.y; else v.y = last.y;
        z[j] = v;                               // NaN only in leading run
    }
    chLast[tid] = last;
    chFirst[tid] = first;
    __syncthreads();                            // S1: wtab + scans visible

    // last observed before this chunk
    float2 pre = make_float2(QNAN, QNAN);
    for (int kk = tid - 1; kk >= 0; --kk) {
        float2 s2 = chLast[kk];
        if (pre.x != pre.x) pre.x = s2.x;
        if (pre.y != pre.y) pre.y = s2.y;
        if (pre.x == pre.x && pre.y == pre.y) break;
    }
    // globally first observed (backward-fill value for the leading prefix)
    float2 gfirst = make_float2(QNAN, QNAN);
    for (int kk = 0; kk < NT; ++kk) {
        float2 s2 = chFirst[kk];
        if (gfirst.x != gfirst.x) gfirst.x = s2.x;
        if (gfirst.y != gfirst.y) gfirst.y = s2.y;
        if (gfirst.x == gfirst.x && gfirst.y == gfirst.y) break;
    }
    if (gfirst.x != gfirst.x) gfirst.x = 0.f;   // all-NaN -> 0
    if (gfirst.y != gfirst.y) gfirst.y = 0.f;
    const float fx = (pre.x == pre.x) ? pre.x : gfirst.x;
    const float fy = (pre.y == pre.y) ? pre.y : gfirst.y;
    const float scale = 1.0f / (float)NFFT;     // prescale -> fp16-safe range
    #pragma unroll
    for (int j = 0; j < 16; ++j) {
        if (z[j].x != z[j].x) z[j].x = fx;
        if (z[j].y != z[j].y) z[j].y = fy;
        z[j].x *= scale; z[j].y *= scale;
    }

    // ---- per-thread twiddle bases (live throughout; R5 body = 104 VGPR) ----
    const float2 wm = wtab[tid];                        // w(m)
    float2 q2 = cmul(wm, wm);
    const float2 w4m = cmul(q2, q2);                    // w(4m)
    const float2 w16r = wtab[16 * (tid & 15)];          // w(16r)
    float2 q3 = cmul(w16r, w16r);
    const float2 w64r = cmul(q3, q3);                   // w(64r)

    const float2 W1 = make_float2( 0.92387953251f,-0.38268343236f); // w(256)
    const float2 W2 = make_float2( 0.70710678119f,-0.70710678119f); // w(512)
    const float2 W3 = make_float2( 0.38268343236f,-0.92387953251f); // w(768)
    const float2 W4 = make_float2( 0.f,-1.f);                       // w(1024)
    const float2 W6 = make_float2(-0.70710678119f,-0.70710678119f); // w(1536)
    const float2 W9 = make_float2(-0.92387953251f, 0.38268343236f); // w(2304)

    __syncthreads();                            // S2: scans done, spech reusable

    // ---- write x_clean/N at P3 (natural time), fp16-packed ----
    #pragma unroll
    for (int j = 0; j < 16; ++j) bufh[pad(16*tid + j)] = packh(z[j].x, z[j].y);
    __syncthreads();                            // S3

    // ================= forward DIF =================
    // phase A on P1 (n = m + 256j)
    #pragma unroll
    for (int j = 0; j < 16; ++j) z[j] = unpackh(bufh[pad(tid + 256*j)]);
    xgrp_fwd(z[0],z[4],z[8],z[12], wm);
    xgrp_fwd(z[1],z[5],z[9],z[13], cmul(wm,W1));
    xgrp_fwd(z[2],z[6],z[10],z[14], cmul(wm,W2));
    xgrp_fwd(z[3],z[7],z[11],z[15], cmul(wm,W3));
    {   float2 w1=w4m, w2=cmul(w1,w1), w3=cmul(w2,w1);
        grp_fwd(z[0],z[1],z[2],z[3],  w1,w2,w3);
        grp_fwd(z[4],z[5],z[6],z[7],  w1,w2,w3);
        grp_fwd(z[8],z[9],z[10],z[11],w1,w2,w3);
        grp_fwd(z[12],z[13],z[14],z[15],w1,w2,w3);
    }
    #pragma unroll
    for (int j = 0; j < 16; ++j) bufh[pad(tid + 256*j)] = packh(z[j].x, z[j].y);
    __syncthreads();                            // S4

    // phase B on P2 (n = (m>>4)*256 + (m&15) + 16j)
    const int p2b = ((tid >> 4) << 8) + (tid & 15);
    #pragma unroll
    for (int j = 0; j < 16; ++j) z[j] = unpackh(bufh[pad(p2b + 16*j)]);
    xgrp_fwd(z[0],z[4],z[8],z[12], w16r);
    xgrp_fwd(z[1],z[5],z[9],z[13], cmul(w16r,W1));
    xgrp_fwd(z[2],z[6],z[10],z[14], cmul(w16r,W2));
    xgrp_fwd(z[3],z[7],z[11],z[15], cmul(w16r,W3));
    {   float2 w1=w64r, w2=cmul(w1,w1), w3=cmul(w2,w1);
        grp_fwd(z[0],z[1],z[2],z[3],  w1,w2,w3);
        grp_fwd(z[4],z[5],z[6],z[7],  w1,w2,w3);
        grp_fwd(z[8],z[9],z[10],z[11],w1,w2,w3);
        grp_fwd(z[12],z[13],z[14],z[15],w1,w2,w3);
    }
    #pragma unroll
    for (int j = 0; j < 16; ++j) bufh[pad(p2b + 16*j)] = packh(z[j].x, z[j].y);
    __syncthreads();                            // S5

    // phase C on P3 (n = 16m + j)
    #pragma unroll
    for (int j = 0; j < 16; ++j) z[j] = unpackh(bufh[pad(16*tid + j)]);
    bf4_fwd(z[0],z[4],z[8],z[12]);
    grp_fwd(z[1],z[5],z[9],z[13], W1,W2,W3);
    grp_fwd(z[2],z[6],z[10],z[14], W2,W4,W6);
    grp_fwd(z[3],z[7],z[11],z[15], W3,W6,W9);
    bf4_fwd(z[0],z[1],z[2],z[3]);
    bf4_fwd(z[4],z[5],z[6],z[7]);
    bf4_fwd(z[8],z[9],z[10],z[11]);
    bf4_fwd(z[12],z[13],z[14],z[15]);

    // ---- park spectrum (already /N) in LDS, fp16-packed, own P3 slots ----
    #pragma unroll
    for (int j = 0; j < 16; ++j) spech[pad(16*tid + j)] = packh(z[j].x, z[j].y);

    // digit-reverse of tid (4 base-4 digits)
    const int revtid = ((tid & 3) << 6) | (((tid >> 2) & 3) << 4)
                     | (((tid >> 4) & 3) << 2) | (tid >> 6);

    // ================= per-filter inverse DIT =================
    #pragma unroll 1
    for (int k = 0; k < KF; ++k) {
        const int tau = taus[k];
        const int mu  = mus[k];
        __syncthreads();                        // prior reads of bufh complete

        // mask + unpack (own P3 slots; spech reads need no extra barrier)
        #pragma unroll
        for (int j = 0; j < 16; ++j) {
            const int r = revtid + ((j & 3) << 10) + ((j >> 2) << 8);
            const int f = (r <= 2048) ? r : (NFFT - r);
            const bool keep = (mu == 1) ? (f < tau) : (f >= tau);
            z[j] = keep ? unpackh(spech[pad(16*tid + j)]) : make_float2(0.f, 0.f);
        }
        // stage0: Y-groups, no twiddle
        bf4_inv(z[0],z[1],z[2],z[3]);
        bf4_inv(z[4],z[5],z[6],z[7]);
        bf4_inv(z[8],z[9],z[10],z[11]);
        bf4_inv(z[12],z[13],z[14],z[15]);
        // stage1: X-groups, k1 = 256*jp (constants)
        bf4_inv(z[0],z[4],z[8],z[12]);
        grp_inv(z[1],z[5],z[9],z[13], W1,W2,W3);
        grp_inv(z[2],z[6],z[10],z[14], W2,W4,W6);
        grp_inv(z[3],z[7],z[11],z[15], W3,W6,W9);
        #pragma unroll
        for (int j = 0; j < 16; ++j) bufh[pad(16*tid + j)] = packh(z[j].x, z[j].y);
        __syncthreads();

        #pragma unroll
        for (int j = 0; j < 16; ++j) z[j] = unpackh(bufh[pad(p2b + 16*j)]);
        // stage2: Y-groups, k1 = 64r
        {   float2 w1=w64r, w2=cmul(w1,w1), w3=cmul(w2,w1);
            grp_inv(z[0],z[1],z[2],z[3],  w1,w2,w3);
            grp_inv(z[4],z[5],z[6],z[7],  w1,w2,w3);
            grp_inv(z[8],z[9],z[10],z[11],w1,w2,w3);
            grp_inv(z[12],z[13],z[14],z[15],w1,w2,w3);
        }
        // stage3: X-groups, k1 = 16r + 256*jp
        xgrp_inv(z[0],z[4],z[8],z[12], w16r);
        xgrp_inv(z[1],z[5],z[9],z[13], cmul(w16r,W1));
        xgrp_inv(z[2],z[6],z[10],z[14], cmul(w16r,W2));
        xgrp_inv(z[3],z[7],z[11],z[15], cmul(w16r,W3));
        #pragma unroll
        for (int j = 0; j < 16; ++j) bufh[pad(p2b + 16*j)] = packh(z[j].x, z[j].y);
        __syncthreads();

        #pragma unroll
        for (int j = 0; j < 16; ++j) z[j] = unpackh(bufh[pad(tid + 256*j)]);
        // stage4: Y-groups, k1 = 4m
        {   float2 w1=w4m, w2=cmul(w1,w1), w3=cmul(w2,w1);
            grp_inv(z[0],z[1],z[2],z[3],  w1,w2,w3);
            grp_inv(z[4],z[5],z[6],z[7],  w1,w2,w3);
            grp_inv(z[8],z[9],z[10],z[11],w1,w2,w3);
            grp_inv(z[12],z[13],z[14],z[15],w1,w2,w3);
        }
        // stage5: X-groups, k1 = m + 256*jp
        xgrp_inv(z[0],z[4],z[8],z[12], wm);
        xgrp_inv(z[1],z[5],z[9],z[13], cmul(wm,W1));
        xgrp_inv(z[2],z[6],z[10],z[14], cmul(wm,W2));
        xgrp_inv(z[3],z[7],z[11],z[15], cmul(wm,W3));

        // store natural order: thread m owns t = m + 256j
        float* ob = out + ((size_t)(k*NB + b) * NFFT) * NC + c0;
        #pragma unroll
        for (int j = 0; j < 16; ++j) {
            const int t = tid + 256*j;
            *reinterpret_cast<float2*>(ob + (size_t)t * NC) = z[j];
        }
    }
}

} // namespace

extern "C" void kernel_launch(void* const* d_in, const int* in_sizes, int n_in,
                              void* d_out, int out_size, void* d_ws, size_t ws_size,
                              hipStream_t stream) {
    (void)in_sizes; (void)n_in; (void)out_size; (void)d_ws; (void)ws_size;
    const float* x  = (const float*)d_in[0];
    const int* taus = (const int*)d_in[1];
    const int* mus  = (const int*)d_in[2];
    float* out      = (float*)d_out;
    dfl_kernel<<<dim3(NB * NC / 2), dim3(NT), 0, stream>>>(x, taus, mus, out);
}

// Round 10
// 101.729 us; speedup vs baseline: 1.2693x; 1.0028x over previous
//
#include <hip/hip_runtime.h>
#include <math.h>

// DecomposedFrequencyLearning: NaN-fill -> rfft(4096) -> 4x freq mask -> irfft
// x[32,4096,64] f32  ->  out[4,32,4096,64] f32
//
// R10 = R9 + raw-barrier replacement. __syncthreads() makes hipcc emit
// s_waitcnt vmcnt(0) before s_barrier, so the 8B/lane stride-256B scattered
// stores of each filter (64 cache lines per wave-inst, ~1024 line-writes per
// wave) must FULLY drain before the next filter starts -- 4 serialized drains
// measured as the ~80% stall (VALUBusy 19.5% matches pure-VALU estimate).
// lds_barrier() = {s_waitcnt lgkmcnt(0); s_barrier}: LDS ordering preserved
// (each wave drains its own LDS ops), global stores stay in flight and
// overlap the next filter's compute. No cross-WG global communication, so
// store order doesn't matter until kernel end.
//
// Structure (R9): one WG per (batch,pair), grid 1024 = one dispatch round at
// 4 WG/CU; single fwd FFT; spectrum parked in LDS fp16-packed; 4x mask+inv.
// LDS: bufh 17408 + spech 17408 + wtab 4096 = 38912 B. VGPR 116 (no clamp --
// (256,4) and waves_per_eu(4) both collapse the target to 64 and spill).
// 1/N prescale keeps fp16 intermediates in range. pad(v)=v+(v>>4).

namespace {

constexpr int NFFT = 4096;
constexpr int NT   = 256;
constexpr int NB   = 32;
constexpr int NC   = 64;
constexpr int KF   = 4;

typedef __fp16 h2 __attribute__((ext_vector_type(2)));

__device__ __forceinline__ int pad(int i) { return i + (i >> 4); }

// LDS-only barrier: wave drains its own LDS ops, then syncs. Global memory
// ops (scattered out-stores) stay in flight across it.
__device__ __forceinline__ void lds_barrier(){
    asm volatile("s_waitcnt lgkmcnt(0)" ::: "memory");
    __builtin_amdgcn_s_barrier();
}

__device__ __forceinline__ unsigned packh(float x, float y){
    h2 h = __builtin_amdgcn_cvt_pkrtz(x, y);   // v_cvt_pkrtz_f16_f32
    return __builtin_bit_cast(unsigned, h);
}
__device__ __forceinline__ float2 unpackh(unsigned u){
    h2 h = __builtin_bit_cast(h2, u);
    return make_float2((float)h.x, (float)h.y);
}

__device__ __forceinline__ float2 cadd(float2 a, float2 b){ return make_float2(a.x+b.x, a.y+b.y); }
__device__ __forceinline__ float2 csub(float2 a, float2 b){ return make_float2(a.x-b.x, a.y-b.y); }
__device__ __forceinline__ float2 cmul(float2 a, float2 b){
    return make_float2(fmaf(a.x,b.x,-(a.y*b.y)), fmaf(a.x,b.y, a.y*b.x));
}
// a * conj(b)
__device__ __forceinline__ float2 cmulc(float2 a, float2 b){
    return make_float2(fmaf(a.x,b.x, a.y*b.y), fmaf(a.y,b.x,-(a.x*b.y)));
}

__device__ __forceinline__ void bf4_fwd(float2&a,float2&b,float2&c,float2&d){
    float2 t0=cadd(a,c), t1=csub(a,c), t2=cadd(b,d), t3=csub(b,d);
    float2 mi3=make_float2(t3.y,-t3.x);          // -i*t3
    a=cadd(t0,t2); b=cadd(t1,mi3); c=csub(t0,t2); d=csub(t1,mi3);
}
__device__ __forceinline__ void bf4_inv(float2&a,float2&b,float2&c,float2&d){
    float2 t0=cadd(a,c), t1=csub(a,c), t2=cadd(b,d), t3=csub(b,d);
    float2 pi3=make_float2(-t3.y,t3.x);          // +i*t3
    a=cadd(t0,t2); b=cadd(t1,pi3); c=csub(t0,t2); d=csub(t1,pi3);
}
// DIF: butterfly then twiddle outputs 1..3
__device__ __forceinline__ void grp_fwd(float2&a,float2&b,float2&c,float2&d,
                                        float2 w1, float2 w2, float2 w3){
    bf4_fwd(a,b,c,d);
    b=cmul(b,w1); c=cmul(c,w2); d=cmul(d,w3);
}
__device__ __forceinline__ void xgrp_fwd(float2&a,float2&b,float2&c,float2&d, float2 w1){
    float2 w2=cmul(w1,w1), w3=cmul(w2,w1);
    grp_fwd(a,b,c,d,w1,w2,w3);
}
// DIT: conj-twiddle inputs 1..3 then butterfly
__device__ __forceinline__ void grp_inv(float2&a,float2&b,float2&c,float2&d,
                                        float2 w1, float2 w2, float2 w3){
    b=cmulc(b,w1); c=cmulc(c,w2); d=cmulc(d,w3);
    bf4_inv(a,b,c,d);
}
__device__ __forceinline__ void xgrp_inv(float2&a,float2&b,float2&c,float2&d, float2 w1){
    float2 w2=cmul(w1,w1), w3=cmul(w2,w1);
    grp_inv(a,b,c,d,w1,w2,w3);
}

__global__ __launch_bounds__(NT)
void dfl_kernel(const float* __restrict__ x,
                const int* __restrict__ taus,
                const int* __restrict__ mus,
                float* __restrict__ out)
{
    __shared__ unsigned bufh[NFFT + NFFT/16];   // 17408 B, half2-packed
    __shared__ unsigned spech[NFFT + NFFT/16];  // 17408 B, half2-packed park
    __shared__ float2 wtab[512];                // 4096 B  (total 38912)

    const int tid = threadIdx.x;
    // XCD-chunked swizzle: the 32 WGs sharing a batch land on one XCD so L2
    // merges their 8B-per-lane partial-line loads/stores.
    const int l  = ((blockIdx.x & 7) << 7) | (blockIdx.x >> 3);
    const int b  = l >> 5;
    const int c0 = (l & 31) << 1;
    const float QNAN = __uint_as_float(0x7fc00000u);

    // w(j) = exp(-2*pi*i*j/4096), j<512
    for (int j = tid; j < 512; j += NT) {
        float s, c; sincosf(-3.14159265358979f * (float)j / 2048.0f, &s, &c);
        wtab[j] = make_float2(c, s);
    }

    // scan scratch aliases the (not-yet-used) spectrum region
    float2* chLast  = reinterpret_cast<float2*>(spech);        // [256]
    float2* chFirst = reinterpret_cast<float2*>(spech) + 256;  // [256]

    // ---- load + in-chunk forward fill (thread t owns times [16t,16t+16)) ----
    const float* xb = x + ((size_t)b * NFFT) * NC + c0;
    float2 z[16];
    float2 last = make_float2(QNAN, QNAN), first = make_float2(QNAN, QNAN);
    #pragma unroll
    for (int j = 0; j < 16; ++j) {
        float2 v = *reinterpret_cast<const float2*>(xb + (size_t)(16*tid + j) * NC);
        if (first.x != first.x && v.x == v.x) first.x = v.x;
        if (first.y != first.y && v.y == v.y) first.y = v.y;
        if (v.x == v.x) last.x = v.x; else v.x = last.x;
        if (v.y == v.y) last.y = v.y; else v.y = last.y;
        z[j] = v;                               // NaN only in leading run
    }
    chLast[tid] = last;
    chFirst[tid] = first;
    lds_barrier();                              // S1: wtab + scans visible

    // last observed before this chunk
    float2 pre = make_float2(QNAN, QNAN);
    for (int kk = tid - 1; kk >= 0; --kk) {
        float2 s2 = chLast[kk];
        if (pre.x != pre.x) pre.x = s2.x;
        if (pre.y != pre.y) pre.y = s2.y;
        if (pre.x == pre.x && pre.y == pre.y) break;
    }
    // globally first observed (backward-fill value for the leading prefix)
    float2 gfirst = make_float2(QNAN, QNAN);
    for (int kk = 0; kk < NT; ++kk) {
        float2 s2 = chFirst[kk];
        if (gfirst.x != gfirst.x) gfirst.x = s2.x;
        if (gfirst.y != gfirst.y) gfirst.y = s2.y;
        if (gfirst.x == gfirst.x && gfirst.y == gfirst.y) break;
    }
    if (gfirst.x != gfirst.x) gfirst.x = 0.f;   // all-NaN -> 0
    if (gfirst.y != gfirst.y) gfirst.y = 0.f;
    const float fx = (pre.x == pre.x) ? pre.x : gfirst.x;
    const float fy = (pre.y == pre.y) ? pre.y : gfirst.y;
    const float scale = 1.0f / (float)NFFT;     // prescale -> fp16-safe range
    #pragma unroll
    for (int j = 0; j < 16; ++j) {
        if (z[j].x != z[j].x) z[j].x = fx;
        if (z[j].y != z[j].y) z[j].y = fy;
        z[j].x *= scale; z[j].y *= scale;
    }

    // ---- per-thread twiddle bases ----
    const float2 wm = wtab[tid];                        // w(m)
    float2 q2 = cmul(wm, wm);
    const float2 w4m = cmul(q2, q2);                    // w(4m)
    const float2 w16r = wtab[16 * (tid & 15)];          // w(16r)
    float2 q3 = cmul(w16r, w16r);
    const float2 w64r = cmul(q3, q3);                   // w(64r)

    const float2 W1 = make_float2( 0.92387953251f,-0.38268343236f); // w(256)
    const float2 W2 = make_float2( 0.70710678119f,-0.70710678119f); // w(512)
    const float2 W3 = make_float2( 0.38268343236f,-0.92387953251f); // w(768)
    const float2 W4 = make_float2( 0.f,-1.f);                       // w(1024)
    const float2 W6 = make_float2(-0.70710678119f,-0.70710678119f); // w(1536)
    const float2 W9 = make_float2(-0.92387953251f, 0.38268343236f); // w(2304)

    lds_barrier();                              // S2: scans done, spech reusable

    // ---- write x_clean/N at P3 (natural time), fp16-packed ----
    #pragma unroll
    for (int j = 0; j < 16; ++j) bufh[pad(16*tid + j)] = packh(z[j].x, z[j].y);
    lds_barrier();                              // S3

    // ================= forward DIF =================
    // phase A on P1 (n = m + 256j)
    #pragma unroll
    for (int j = 0; j < 16; ++j) z[j] = unpackh(bufh[pad(tid + 256*j)]);
    xgrp_fwd(z[0],z[4],z[8],z[12], wm);
    xgrp_fwd(z[1],z[5],z[9],z[13], cmul(wm,W1));
    xgrp_fwd(z[2],z[6],z[10],z[14], cmul(wm,W2));
    xgrp_fwd(z[3],z[7],z[11],z[15], cmul(wm,W3));
    {   float2 w1=w4m, w2=cmul(w1,w1), w3=cmul(w2,w1);
        grp_fwd(z[0],z[1],z[2],z[3],  w1,w2,w3);
        grp_fwd(z[4],z[5],z[6],z[7],  w1,w2,w3);
        grp_fwd(z[8],z[9],z[10],z[11],w1,w2,w3);
        grp_fwd(z[12],z[13],z[14],z[15],w1,w2,w3);
    }
    #pragma unroll
    for (int j = 0; j < 16; ++j) bufh[pad(tid + 256*j)] = packh(z[j].x, z[j].y);
    lds_barrier();                              // S4

    // phase B on P2 (n = (m>>4)*256 + (m&15) + 16j)
    const int p2b = ((tid >> 4) << 8) + (tid & 15);
    #pragma unroll
    for (int j = 0; j < 16; ++j) z[j] = unpackh(bufh[pad(p2b + 16*j)]);
    xgrp_fwd(z[0],z[4],z[8],z[12], w16r);
    xgrp_fwd(z[1],z[5],z[9],z[13], cmul(w16r,W1));
    xgrp_fwd(z[2],z[6],z[10],z[14], cmul(w16r,W2));
    xgrp_fwd(z[3],z[7],z[11],z[15], cmul(w16r,W3));
    {   float2 w1=w64r, w2=cmul(w1,w1), w3=cmul(w2,w1);
        grp_fwd(z[0],z[1],z[2],z[3],  w1,w2,w3);
        grp_fwd(z[4],z[5],z[6],z[7],  w1,w2,w3);
        grp_fwd(z[8],z[9],z[10],z[11],w1,w2,w3);
        grp_fwd(z[12],z[13],z[14],z[15],w1,w2,w3);
    }
    #pragma unroll
    for (int j = 0; j < 16; ++j) bufh[pad(p2b + 16*j)] = packh(z[j].x, z[j].y);
    lds_barrier();                              // S5

    // phase C on P3 (n = 16m + j)
    #pragma unroll
    for (int j = 0; j < 16; ++j) z[j] = unpackh(bufh[pad(16*tid + j)]);
    bf4_fwd(z[0],z[4],z[8],z[12]);
    grp_fwd(z[1],z[5],z[9],z[13], W1,W2,W3);
    grp_fwd(z[2],z[6],z[10],z[14], W2,W4,W6);
    grp_fwd(z[3],z[7],z[11],z[15], W3,W6,W9);
    bf4_fwd(z[0],z[1],z[2],z[3]);
    bf4_fwd(z[4],z[5],z[6],z[7]);
    bf4_fwd(z[8],z[9],z[10],z[11]);
    bf4_fwd(z[12],z[13],z[14],z[15]);

    // ---- park spectrum (already /N) in LDS, fp16-packed, own P3 slots ----
    #pragma unroll
    for (int j = 0; j < 16; ++j) spech[pad(16*tid + j)] = packh(z[j].x, z[j].y);

    // digit-reverse of tid (4 base-4 digits)
    const int revtid = ((tid & 3) << 6) | (((tid >> 2) & 3) << 4)
                     | (((tid >> 4) & 3) << 2) | (tid >> 6);

    // ================= per-filter inverse DIT =================
    #pragma unroll 1
    for (int k = 0; k < KF; ++k) {
        const int tau = taus[k];
        const int mu  = mus[k];
        lds_barrier();          // prior bufh reads done; stores stay in flight

        // mask + unpack (own P3 slots; spech reads need no extra barrier)
        #pragma unroll
        for (int j = 0; j < 16; ++j) {
            const int r = revtid + ((j & 3) << 10) + ((j >> 2) << 8);
            const int f = (r <= 2048) ? r : (NFFT - r);
            const bool keep = (mu == 1) ? (f < tau) : (f >= tau);
            z[j] = keep ? unpackh(spech[pad(16*tid + j)]) : make_float2(0.f, 0.f);
        }
        // stage0: Y-groups, no twiddle
        bf4_inv(z[0],z[1],z[2],z[3]);
        bf4_inv(z[4],z[5],z[6],z[7]);
        bf4_inv(z[8],z[9],z[10],z[11]);
        bf4_inv(z[12],z[13],z[14],z[15]);
        // stage1: X-groups, k1 = 256*jp (constants)
        bf4_inv(z[0],z[4],z[8],z[12]);
        grp_inv(z[1],z[5],z[9],z[13], W1,W2,W3);
        grp_inv(z[2],z[6],z[10],z[14], W2,W4,W6);
        grp_inv(z[3],z[7],z[11],z[15], W3,W6,W9);
        #pragma unroll
        for (int j = 0; j < 16; ++j) bufh[pad(16*tid + j)] = packh(z[j].x, z[j].y);
        lds_barrier();

        #pragma unroll
        for (int j = 0; j < 16; ++j) z[j] = unpackh(bufh[pad(p2b + 16*j)]);
        // stage2: Y-groups, k1 = 64r
        {   float2 w1=w64r, w2=cmul(w1,w1), w3=cmul(w2,w1);
            grp_inv(z[0],z[1],z[2],z[3],  w1,w2,w3);
            grp_inv(z[4],z[5],z[6],z[7],  w1,w2,w3);
            grp_inv(z[8],z[9],z[10],z[11],w1,w2,w3);
            grp_inv(z[12],z[13],z[14],z[15],w1,w2,w3);
        }
        // stage3: X-groups, k1 = 16r + 256*jp
        xgrp_inv(z[0],z[4],z[8],z[12], w16r);
        xgrp_inv(z[1],z[5],z[9],z[13], cmul(w16r,W1));
        xgrp_inv(z[2],z[6],z[10],z[14], cmul(w16r,W2));
        xgrp_inv(z[3],z[7],z[11],z[15], cmul(w16r,W3));
        #pragma unroll
        for (int j = 0; j < 16; ++j) bufh[pad(p2b + 16*j)] = packh(z[j].x, z[j].y);
        lds_barrier();

        #pragma unroll
        for (int j = 0; j < 16; ++j) z[j] = unpackh(bufh[pad(tid + 256*j)]);
        // stage4: Y-groups, k1 = 4m
        {   float2 w1=w4m, w2=cmul(w1,w1), w3=cmul(w2,w1);
            grp_inv(z[0],z[1],z[2],z[3],  w1,w2,w3);
            grp_inv(z[4],z[5],z[6],z[7],  w1,w2,w3);
            grp_inv(z[8],z[9],z[10],z[11],w1,w2,w3);
            grp_inv(z[12],z[13],z[14],z[15],w1,w2,w3);
        }
        // stage5: X-groups, k1 = m + 256*jp
        xgrp_inv(z[0],z[4],z[8],z[12], wm);
        xgrp_inv(z[1],z[5],z[9],z[13], cmul(wm,W1));
        xgrp_inv(z[2],z[6],z[10],z[14], cmul(wm,W2));
        xgrp_inv(z[3],z[7],z[11],z[15], cmul(wm,W3));

        // store natural order: thread m owns t = m + 256j (stays in flight
        // across the next filter's lds_barrier -- no vmcnt drain)
        float* ob = out + ((size_t)(k*NB + b) * NFFT) * NC + c0;
        #pragma unroll
        for (int j = 0; j < 16; ++j) {
            const int t = tid + 256*j;
            *reinterpret_cast<float2*>(ob + (size_t)t * NC) = z[j];
        }
    }
}

} // namespace

extern "C" void kernel_launch(void* const* d_in, const int* in_sizes, int n_in,
                              void* d_out, int out_size, void* d_ws, size_t ws_size,
                              hipStream_t stream) {
    (void)in_sizes; (void)n_in; (void)out_size; (void)d_ws; (void)ws_size;
    const float* x  = (const float*)d_in[0];
    const int* taus = (const int*)d_in[1];
    const int* mus  = (const int*)d_in[2];
    float* out      = (float*)d_out;
    dfl_kernel<<<dim3(NB * NC / 2), dim3(NT), 0, stream>>>(x, taus, mus, out);
}